// Round 4
// baseline (749.651 us; speedup 1.0000x reference)
//
#include <hip/hip_runtime.h>

// TargetModel_78786880077968: 2-layer GCN + mean pool
#define NN 100000      // nodes
#define NE 1600000     // edges
#define NG 512         // graphs
#define FD 64          // feature dim (IN_DIM == HID == 64)
#define SCAN_CHUNK 1024
#define SCAN_BLOCKS 98  // ceil(NN / SCAN_CHUNK)

// ---- bf16 pack/unpack (RNE; values are finite) ----
__device__ inline unsigned pack_bf16x2(float a, float b) {
    unsigned ua = __float_as_uint(a), ub = __float_as_uint(b);
    ua = (ua + 0x7FFFu + ((ua >> 16) & 1u)) >> 16;
    ub = (ub + 0x7FFFu + ((ub >> 16) & 1u)) >> 16;
    return ua | (ub << 16);
}
__device__ inline float bf_lo(unsigned u) { return __uint_as_float(u << 16); }
__device__ inline float bf_hi(unsigned u) { return __uint_as_float(u & 0xFFFF0000u); }

// ---------- CSR build ----------

__global__ void k_count_rank(const int* __restrict__ dst, int* __restrict__ cnt,
                             int* __restrict__ rank, int e) {
    int i = blockIdx.x * 256 + threadIdx.x;
    if (i < e) rank[i] = atomicAdd(&cnt[dst[i]], 1);
}

__global__ void k_scan1(const int* __restrict__ cnt, int* __restrict__ part,
                        int* __restrict__ blockSum, int n) {
    __shared__ int lds[256];
    int tid = threadIdx.x;
    int base = blockIdx.x * SCAN_CHUNK + tid * 4;
    int v0 = (base + 0 < n) ? cnt[base + 0] : 0;
    int v1 = (base + 1 < n) ? cnt[base + 1] : 0;
    int v2 = (base + 2 < n) ? cnt[base + 2] : 0;
    int v3 = (base + 3 < n) ? cnt[base + 3] : 0;
    int s = v0 + v1 + v2 + v3;
    lds[tid] = s;
    __syncthreads();
    for (int off = 1; off < 256; off <<= 1) {
        int t = (tid >= off) ? lds[tid - off] : 0;
        __syncthreads();
        lds[tid] += t;
        __syncthreads();
    }
    int run = lds[tid] - s;
    if (base + 0 < n) part[base + 0] = run; run += v0;
    if (base + 1 < n) part[base + 1] = run; run += v1;
    if (base + 2 < n) part[base + 2] = run; run += v2;
    if (base + 3 < n) part[base + 3] = run;
    if (tid == 255) blockSum[blockIdx.x] = lds[255];
}

__global__ void k_scan2(const int* __restrict__ bs, int* __restrict__ boff, int nb) {
    __shared__ int lds[128];
    int tid = threadIdx.x;
    int v = (tid < nb) ? bs[tid] : 0;
    lds[tid] = v;
    __syncthreads();
    for (int off = 1; off < 128; off <<= 1) {
        int t = (tid >= off) ? lds[tid - off] : 0;
        __syncthreads();
        lds[tid] += t;
        __syncthreads();
    }
    if (tid < nb) boff[tid] = lds[tid] - v;
}

__global__ void k_scan3(int* __restrict__ rowptr, const int* __restrict__ boff,
                        const int* __restrict__ cnt, float* __restrict__ dinv,
                        const int* __restrict__ batch, int* __restrict__ pcnt, int n) {
    int i = blockIdx.x * 256 + threadIdx.x;
    if (i < n) {
        rowptr[i] = rowptr[i] + boff[i >> 10];
        float deg = (float)(cnt[i] + 1);  // +1 self loop
        dinv[i] = 1.0f / sqrtf(deg);
        atomicAdd(&pcnt[batch[i]], 1);
    }
}

__global__ void k_fill(const int* __restrict__ src, const int* __restrict__ dst,
                       const int* __restrict__ rank, const int* __restrict__ rowptr,
                       int* __restrict__ colidx, int e) {
    int i = blockIdx.x * 256 + threadIdx.x;
    if (i < e) {
        int d = dst[i];
        colidx[rowptr[d] + rank[i]] = src[i];
    }
}

// ---------- dense: out[n][f] = bf16( dinv[n] * sum_k in[n][k] * W[k][f] ) ----------
// 4 waves/block, 4 rows/wave; 16 lanes per row, lane computes 4 features; W in LDS.
template <int BF16IN>
__global__ void k_gemm_scale(const void* __restrict__ inv_, const float* __restrict__ W,
                             const float* __restrict__ dinv, unsigned* __restrict__ out, int n) {
    __shared__ float w[FD * FD];        // 16 KB
    __shared__ float xr[4][4][80];      // padded f32 row staging
    int tid = threadIdx.x;
    {
        const float4* W4 = (const float4*)W;
        float4* w4s = (float4*)w;
        for (int i = tid; i < FD * FD / 4; i += 256) w4s[i] = W4[i];
    }
    int wave = tid >> 6, lane = tid & 63;
    int r = lane >> 4;        // row within wave
    int c = lane & 15;        // 4-feature chunk
    int row = blockIdx.x * 16 + wave * 4 + r;
    bool valid = row < n;
    if (valid) {
        if (BF16IN) {
            uint2 v = ((const uint2*)inv_)[row * 16 + c];
            xr[wave][r][c * 4 + 0] = bf_lo(v.x);
            xr[wave][r][c * 4 + 1] = bf_hi(v.x);
            xr[wave][r][c * 4 + 2] = bf_lo(v.y);
            xr[wave][r][c * 4 + 3] = bf_hi(v.y);
        } else {
            float4 xv = ((const float4*)inv_)[row * 16 + c];
            *((float4*)&xr[wave][r][c * 4]) = xv;
        }
    }
    __syncthreads();
    if (!valid) return;
    const float4* w4 = (const float4*)w;   // w4[k*16 + c]
    float4 acc = {0.f, 0.f, 0.f, 0.f};
#pragma unroll
    for (int k = 0; k < FD; ++k) {
        float xv = xr[wave][r][k];
        float4 wv = w4[k * 16 + c];
        acc.x = fmaf(xv, wv.x, acc.x);
        acc.y = fmaf(xv, wv.y, acc.y);
        acc.z = fmaf(xv, wv.z, acc.z);
        acc.w = fmaf(xv, wv.w, acc.w);
    }
    float d = dinv[row];
    uint2 o;
    o.x = pack_bf16x2(acc.x * d, acc.y * d);
    o.y = pack_bf16x2(acc.z * d, acc.w * d);
    ((uint2*)out)[row * 16 + c] = o;
}

// ---------- aggregation: wave per node, bf16 rows (128 B), 8 neighbor slots ----------
// sum = hs[node] + sum_{e: dst=node} hs[src_e];  res = relu(dinv*sum + b)
template <int POOL>
__global__ void k_agg(const unsigned* __restrict__ hs, const int* __restrict__ rowptr,
                      const int* __restrict__ cnt, const int* __restrict__ colidx,
                      const float* __restrict__ dinv, const float* __restrict__ b,
                      const int* __restrict__ batch, float* __restrict__ outp, int n) {
    int tid = threadIdx.x;
    int wave = tid >> 6, lane = tid & 63;
    int node = blockIdx.x * 4 + wave;
    if (node >= n) return;
    int g = lane >> 3;        // neighbor slot 0..7
    int c = lane & 7;         // 16 B chunk (8 bf16 features)
    const uint4* hsv = (const uint4*)hs;   // row = 8 uint4
    uint4 self = hsv[node * 8 + c];        // issue early
    float acc[8];
#pragma unroll
    for (int j = 0; j < 8; ++j) acc[j] = 0.f;
    int s = rowptr[node], e = s + cnt[node];
    int i = s;
    for (; i + 16 <= e; i += 16) {
        int n0 = colidx[i + g];
        int n1 = colidx[i + 8 + g];
        uint4 v0 = hsv[n0 * 8 + c];
        uint4 v1 = hsv[n1 * 8 + c];
        acc[0] += bf_lo(v0.x); acc[1] += bf_hi(v0.x);
        acc[2] += bf_lo(v0.y); acc[3] += bf_hi(v0.y);
        acc[4] += bf_lo(v0.z); acc[5] += bf_hi(v0.z);
        acc[6] += bf_lo(v0.w); acc[7] += bf_hi(v0.w);
        acc[0] += bf_lo(v1.x); acc[1] += bf_hi(v1.x);
        acc[2] += bf_lo(v1.y); acc[3] += bf_hi(v1.y);
        acc[4] += bf_lo(v1.z); acc[5] += bf_hi(v1.z);
        acc[6] += bf_lo(v1.w); acc[7] += bf_hi(v1.w);
    }
    if (i + 8 <= e) {
        int n0 = colidx[i + g];
        uint4 v0 = hsv[n0 * 8 + c];
        acc[0] += bf_lo(v0.x); acc[1] += bf_hi(v0.x);
        acc[2] += bf_lo(v0.y); acc[3] += bf_hi(v0.y);
        acc[4] += bf_lo(v0.z); acc[5] += bf_hi(v0.z);
        acc[6] += bf_lo(v0.w); acc[7] += bf_hi(v0.w);
        i += 8;
    }
    int rem = e - i;          // 0..7
    if (g < rem) {
        int n0 = colidx[i + g];
        uint4 v0 = hsv[n0 * 8 + c];
        acc[0] += bf_lo(v0.x); acc[1] += bf_hi(v0.x);
        acc[2] += bf_lo(v0.y); acc[3] += bf_hi(v0.y);
        acc[4] += bf_lo(v0.z); acc[5] += bf_hi(v0.z);
        acc[6] += bf_lo(v0.w); acc[7] += bf_hi(v0.w);
    }
    // reduce across the 8 neighbor-slot groups
#pragma unroll
    for (int j = 0; j < 8; ++j) {
        acc[j] += __shfl_xor(acc[j], 8, 64);
        acc[j] += __shfl_xor(acc[j], 16, 64);
        acc[j] += __shfl_xor(acc[j], 32, 64);
    }
    // self loop (added post-reduce; only group 0 writes)
    acc[0] += bf_lo(self.x); acc[1] += bf_hi(self.x);
    acc[2] += bf_lo(self.y); acc[3] += bf_hi(self.y);
    acc[4] += bf_lo(self.z); acc[5] += bf_hi(self.z);
    acc[6] += bf_lo(self.w); acc[7] += bf_hi(self.w);
    float d = dinv[node];
    float4 bb0 = ((const float4*)b)[c * 2 + 0];
    float4 bb1 = ((const float4*)b)[c * 2 + 1];
    float res[8];
    res[0] = fmaxf(fmaf(acc[0], d, bb0.x), 0.f);
    res[1] = fmaxf(fmaf(acc[1], d, bb0.y), 0.f);
    res[2] = fmaxf(fmaf(acc[2], d, bb0.z), 0.f);
    res[3] = fmaxf(fmaf(acc[3], d, bb0.w), 0.f);
    res[4] = fmaxf(fmaf(acc[4], d, bb1.x), 0.f);
    res[5] = fmaxf(fmaf(acc[5], d, bb1.y), 0.f);
    res[6] = fmaxf(fmaf(acc[6], d, bb1.z), 0.f);
    res[7] = fmaxf(fmaf(acc[7], d, bb1.w), 0.f);
    if (g == 0) {
        if (POOL) {
            float* p = &outp[batch[node] * FD + c * 8];
#pragma unroll
            for (int j = 0; j < 8; ++j) atomicAdd(p + j, res[j]);
        } else {
            uint4 o;
            o.x = pack_bf16x2(res[0], res[1]);
            o.y = pack_bf16x2(res[2], res[3]);
            o.z = pack_bf16x2(res[4], res[5]);
            o.w = pack_bf16x2(res[6], res[7]);
            ((uint4*)outp)[node * 8 + c] = o;
        }
    }
}

// out[g][o] = (sum_f pool[g][f]/cnt[g] * Wfc[f][o]) + bfc[o];  wave per graph
__global__ void k_final(const float* __restrict__ pool, const int* __restrict__ pcnt,
                        const float* __restrict__ Wfc, const float* __restrict__ bfc,
                        float* __restrict__ out, int ng) {
    int tid = threadIdx.x;
    int wave = tid >> 6, lane = tid & 63;
    int g = blockIdx.x * 4 + wave;
    if (g >= ng) return;
    float inv = 1.0f / fmaxf((float)pcnt[g], 1.0f);
    float s = pool[g * FD + lane] * inv;
    float a0 = s * Wfc[lane * 2 + 0];
    float a1 = s * Wfc[lane * 2 + 1];
#pragma unroll
    for (int off = 32; off > 0; off >>= 1) {
        a0 += __shfl_down(a0, off, 64);
        a1 += __shfl_down(a1, off, 64);
    }
    if (lane == 0) {
        out[g * 2 + 0] = a0 + bfc[0];
        out[g * 2 + 1] = a1 + bfc[1];
    }
}

extern "C" void kernel_launch(void* const* d_in, const int* in_sizes, int n_in,
                              void* d_out, int out_size, void* d_ws, size_t ws_size,
                              hipStream_t stream) {
    const float* x    = (const float*)d_in[0];
    const int*   eidx = (const int*)d_in[1];   // [2][NE]: row0 = src, row1 = dst
    const int*   batch= (const int*)d_in[2];
    const float* W1   = (const float*)d_in[3];
    const float* b1   = (const float*)d_in[4];
    const float* W2   = (const float*)d_in[5];
    const float* b2   = (const float*)d_in[6];
    const float* Wfc  = (const float*)d_in[7];
    const float* bfc  = (const float*)d_in[8];
    float* out = (float*)d_out;

    const int* esrc = eidx;
    const int* edst = eidx + NE;

    char* ws = (char*)d_ws;
    size_t off = 0;
    auto alloc = [&](size_t bytes) {
        char* p = ws + off;
        off += (bytes + 255) & ~(size_t)255;
        return p;
    };
    int*      cnt      = (int*)     alloc(NN * 4);
    int*      rowptr   = (int*)     alloc(NN * 4);
    int*      blockSum = (int*)     alloc(128 * 4);
    int*      blockOff = (int*)     alloc(128 * 4);
    float*    dinv     = (float*)   alloc(NN * 4);
    int*      colidx   = (int*)     alloc((size_t)NE * 4);
    unsigned* hs       = (unsigned*)alloc((size_t)NN * FD * 2);   // bf16
    unsigned* h1       = (unsigned*)alloc((size_t)NN * FD * 2);   // bf16
    float*    pool     = (float*)   alloc((size_t)NG * FD * 4);
    int*      pcnt     = (int*)     alloc(NG * 4);
    // rank aliases h1 (rank last used in k_fill, h1 first written by k_agg<0>)
    int*      rank     = (int*)h1;
    (void)ws_size;

    hipMemsetAsync(cnt,  0, NN * 4, stream);
    hipMemsetAsync(pool, 0, (size_t)NG * FD * 4, stream);
    hipMemsetAsync(pcnt, 0, NG * 4, stream);

    const int GE = (NE + 255) / 256;   // 6250
    const int GN = (NN + 255) / 256;   // 391
    const int GW = (NN + 3) / 4;       // wave-per-node kernels
    const int GR = (NN + 15) / 16;     // gemm: 16 rows/block

    k_count_rank<<<GE, 256, 0, stream>>>(edst, cnt, rank, NE);
    k_scan1<<<SCAN_BLOCKS, 256, 0, stream>>>(cnt, rowptr, blockSum, NN);
    k_scan2<<<1, 128, 0, stream>>>(blockSum, blockOff, SCAN_BLOCKS);
    k_scan3<<<GN, 256, 0, stream>>>(rowptr, blockOff, cnt, dinv, batch, pcnt, NN);
    k_fill<<<GE, 256, 0, stream>>>(esrc, edst, rank, rowptr, colidx, NE);

    // layer 1
    k_gemm_scale<0><<<GR, 256, 0, stream>>>(x, W1, dinv, hs, NN);
    k_agg<0><<<GW, 256, 0, stream>>>(hs, rowptr, cnt, colidx, dinv, b1, batch, (float*)h1, NN);

    // layer 2 (pool fused into aggregation epilogue)
    k_gemm_scale<1><<<GR, 256, 0, stream>>>(h1, W2, dinv, hs, NN);
    k_agg<1><<<GW, 256, 0, stream>>>(hs, rowptr, cnt, colidx, dinv, b2, batch, pool, NN);

    // readout
    k_final<<<(NG + 3) / 4, 256, 0, stream>>>(pool, pcnt, Wfc, bfc, out, NG);
}